// Round 2
// baseline (6092.452 us; speedup 1.0000x reference)
//
#include <hip/hip_runtime.h>

#define NB 32
#define NT 512
#define NI 128
#define NH 1024
#define NG 4096
#define NO 128

typedef _Float16 f16;
typedef _Float16 f16x8 __attribute__((ext_vector_type(8)));
typedef float f32x4 __attribute__((ext_vector_type(4)));

__device__ __forceinline__ float sigm(float x) { return 1.f / (1.f + __expf(-x)); }
__device__ __forceinline__ float tanh_(float x) {
    float a = fabsf(x);
    float e = __expf(-2.f * a);
    float r = (1.f - e) / (1.f + e);
    return x < 0.f ? -r : r;
}

__global__ void convf16(const float* __restrict__ src, f16* __restrict__ dst, int n) {
    int i = blockIdx.x * blockDim.x + threadIdx.x;
    if (i < n) dst[i] = (f16)src[i];
}

// ---------------------------------------------------------------------------
// Persistent pipeline kernel. 256 WGs x 256 threads, 1 WG/CU (forced by LDS).
//   WG [0,128)   R1: layer-1 LSTM step, (16 batch, 16 units) per CU.
//                LDS: [W_ih0;W_hh0] slice in frag order, K=1152, 144 KB.
//   WG [128,192) P : xp2[t] = h1[t] @ W_ih1^T (no bias), 16 units (64 cols)/CU.
//   WG [192,256) R2: layer-2 LSTM step, full batch, 16 units per CU,
//                consumes xp2 ring (depth 16) + W_hh1 slice in LDS.
// Sync: per-(t,cu) flags in L3. Publishes via agent-scope atomic stores
// (bypass per-XCD L2); consumers do plain loads of fresh-per-t addresses
// after an agent acquire fence each step.
// ---------------------------------------------------------------------------
extern "C" __global__ __launch_bounds__(256, 1) void persist(
    const float* __restrict__ Wih0f, const float* __restrict__ Whh0f, const float* __restrict__ b0,
    const float* __restrict__ Wih1f, const float* __restrict__ Whh1f, const float* __restrict__ b1,
    const f16* __restrict__ state16,
    f16* __restrict__ h1all,      // [NT][NB][NH]
    f16* __restrict__ h2all,      // [NT][NB][NH]
    float* __restrict__ xp2ring,  // [16][NB][NG]
    unsigned* __restrict__ flags1,  // [NT][128]
    unsigned* __restrict__ flagsp,  // [NT][64]
    unsigned* __restrict__ flags2)  // [NT][64]
{
    extern __shared__ char smem[];
    const int bid = blockIdx.x;
    const int tid = threadIdx.x;
    const int w = tid >> 6;         // wave = gate index (col tile)
    const int lane = tid & 63;
    const int llo = lane & 15;
    const int lhi = lane >> 4;

    if (bid < 128) {
        // =================== R1 ===================
        const int bs = bid >> 6, us = bid & 63;
        const int bbase = bs * 16, ubase = us * 16;
        const int KST = 36;  // K=1152 (128 state + 1024 h)

        // stage W slice into LDS in fragment order
        for (int idx = tid; idx < 4 * KST * 64; idx += 256) {
            int ln = idx & 63;
            int kst = (idx >> 6) % KST;
            int ct = idx / (64 * KST);
            int col = ct * NH + ubase + (ln & 15);
            int kpos = kst * 32 + (ln >> 4) * 8;
            const float* s = (kpos < 128) ? (Wih0f + (size_t)col * NI + kpos)
                                          : (Whh0f + (size_t)col * NH + (kpos - 128));
            float4 x0 = *(const float4*)s;
            float4 x1 = *(const float4*)(s + 4);
            f16x8 v;
            v[0] = (f16)x0.x; v[1] = (f16)x0.y; v[2] = (f16)x0.z; v[3] = (f16)x0.w;
            v[4] = (f16)x1.x; v[5] = (f16)x1.y; v[6] = (f16)x1.z; v[7] = (f16)x1.w;
            *(f16x8*)(smem + (size_t)idx * 16) = v;
        }
        char* WL = smem;
        char* Ab0 = smem + 147456;
        char* Ab1 = smem + 147456 + 4096;
        float* gbuf = (float*)Ab1;  // overlay: used only after last chunk consumed

        const int j = tid & 15, row = tid >> 4;  // elementwise mapping (16x16)
        const float bi = b0[0 * NH + ubase + j];
        const float bf = b0[1 * NH + ubase + j];
        const float bg = b0[2 * NH + ubase + j];
        const float bo = b0[3 * NH + ubase + j];
        float c_ = 0.f;
        __syncthreads();

        for (int t = 0; t < NT; ++t) {
            if (w == 0) {
                if (t > 0) {
                    const unsigned* fl = flags1 + (size_t)(t - 1) * 128 + bs * 64;
                    while (!__all((int)__hip_atomic_load(fl + lane, __ATOMIC_RELAXED,
                                                         __HIP_MEMORY_SCOPE_AGENT)))
                        __builtin_amdgcn_s_sleep(1);
                }
                __builtin_amdgcn_fence(__ATOMIC_ACQUIRE, "agent");
            }
            __syncthreads();

            auto stageA = [&](int c) {
                int k2 = tid >> 6, ln = tid & 63;
                int kpos = c * 128 + k2 * 32 + (ln >> 4) * 8;
                int rw = bbase + (ln & 15);
                f16x8 v;
                if (kpos < 128)
                    v = *(const f16x8*)(state16 + ((size_t)rw * NT + t) * NI + kpos);
                else if (t > 0)
                    v = *(const f16x8*)(h1all + ((size_t)(t - 1) * NB + rw) * NH + (kpos - 128));
                else
                    v = f16x8{};
                *(f16x8*)(((c & 1) ? Ab1 : Ab0) + tid * 16) = v;
            };

            stageA(0);
            __syncthreads();
            f32x4 acc0 = {}, acc1 = {};
            for (int ch = 0; ch < 9; ++ch) {
                if (ch < 8) stageA(ch + 1);
                const char* ab = (ch & 1) ? Ab1 : Ab0;
#pragma unroll
                for (int k2 = 0; k2 < 4; ++k2) {
                    int ks = ch * 4 + k2;
                    f16x8 a = *(const f16x8*)(ab + ((k2 << 6) + lane) * 16);
                    f16x8 bfr = *(const f16x8*)(WL + (((size_t)(w * KST + ks) << 6) + lane) * 16);
                    if (k2 & 1) acc1 = __builtin_amdgcn_mfma_f32_16x16x32_f16(a, bfr, acc1, 0, 0, 0);
                    else        acc0 = __builtin_amdgcn_mfma_f32_16x16x32_f16(a, bfr, acc0, 0, 0, 0);
                }
                __syncthreads();
            }
            f32x4 g = acc0 + acc1;
#pragma unroll
            for (int r = 0; r < 4; ++r)
                gbuf[(w * 16 + lhi * 4 + r) * 16 + llo] = g[r];
            __syncthreads();
            {
                float gi = gbuf[(0 * 16 + row) * 16 + j] + bi;
                float gf = gbuf[(1 * 16 + row) * 16 + j] + bf;
                float gg = gbuf[(2 * 16 + row) * 16 + j] + bg;
                float go = gbuf[(3 * 16 + row) * 16 + j] + bo;
                float i_ = sigm(gi), f_ = sigm(gf), g_ = tanh_(gg), o_ = sigm(go);
                c_ = f_ * c_ + i_ * g_;
                float h = o_ * tanh_(c_);
                unsigned short hb = __builtin_bit_cast(unsigned short, (f16)h);
                __hip_atomic_store((unsigned short*)(h1all + ((size_t)t * NB + bbase + row) * NH + ubase + j),
                                   hb, __ATOMIC_RELAXED, __HIP_MEMORY_SCOPE_AGENT);
            }
            __syncthreads();
            if (tid == 0) {
                __builtin_amdgcn_fence(__ATOMIC_RELEASE, "agent");
                __hip_atomic_store(flags1 + (size_t)t * 128 + bid, 1u,
                                   __ATOMIC_RELAXED, __HIP_MEMORY_SCOPE_AGENT);
            }
        }
    } else {
        // =================== P and R2 (shared structure, K=1024) ===================
        const bool isP = (bid < 192);
        const int q = isP ? (bid - 128) : (bid - 192);
        const int ubase = q * 16;
        const int KST = 32;
        const float* Wsrc = isP ? Wih1f : Whh1f;

        for (int idx = tid; idx < 4 * KST * 64; idx += 256) {
            int ln = idx & 63;
            int kst = (idx >> 6) % KST;
            int ct = idx / (64 * KST);
            int col = ct * NH + ubase + (ln & 15);
            int kpos = kst * 32 + (ln >> 4) * 8;
            const float* s = Wsrc + (size_t)col * NH + kpos;
            float4 x0 = *(const float4*)s;
            float4 x1 = *(const float4*)(s + 4);
            f16x8 v;
            v[0] = (f16)x0.x; v[1] = (f16)x0.y; v[2] = (f16)x0.z; v[3] = (f16)x0.w;
            v[4] = (f16)x1.x; v[5] = (f16)x1.y; v[6] = (f16)x1.z; v[7] = (f16)x1.w;
            *(f16x8*)(smem + (size_t)idx * 16) = v;
        }
        char* WL = smem;
        char* Ab0 = smem + 131072;
        char* Ab1 = smem + 131072 + 8192;
        float* gbuf = (float*)Ab0;  // R2 only; safe overlay

        const float biasw = isP ? 0.f : b1[w * NH + ubase + llo];
        const int j = tid & 15, r0 = tid >> 4;  // R2 elementwise
        const float bi = b1[0 * NH + ubase + j];
        const float bf = b1[1 * NH + ubase + j];
        const float bg = b1[2 * NH + ubase + j];
        const float bo = b1[3 * NH + ubase + j];
        (void)bi; (void)bf; (void)bg; (void)bo; (void)biasw;
        float cA = 0.f, cB = 0.f;
        __syncthreads();

        for (int t = 0; t < NT; ++t) {
            if (w == 0) {
                if (isP) {
                    for (;;) {
                        int ok = (int)__hip_atomic_load(flags1 + (size_t)t * 128 + lane,
                                                        __ATOMIC_RELAXED, __HIP_MEMORY_SCOPE_AGENT) &&
                                 (int)__hip_atomic_load(flags1 + (size_t)t * 128 + 64 + lane,
                                                        __ATOMIC_RELAXED, __HIP_MEMORY_SCOPE_AGENT);
                        if (t >= 16)
                            ok = ok && (int)__hip_atomic_load(flags2 + (size_t)(t - 16) * 64 + lane,
                                                              __ATOMIC_RELAXED, __HIP_MEMORY_SCOPE_AGENT);
                        if (__all(ok)) break;
                        __builtin_amdgcn_s_sleep(1);
                    }
                } else {
                    for (;;) {
                        int ok = (int)__hip_atomic_load(flagsp + (size_t)t * 64 + q,
                                                        __ATOMIC_RELAXED, __HIP_MEMORY_SCOPE_AGENT);
                        if (t > 0)
                            ok = ok && (int)__hip_atomic_load(flags2 + (size_t)(t - 1) * 64 + lane,
                                                              __ATOMIC_RELAXED, __HIP_MEMORY_SCOPE_AGENT);
                        if (__all(ok)) break;
                        __builtin_amdgcn_s_sleep(1);
                    }
                }
                __builtin_amdgcn_fence(__ATOMIC_ACQUIRE, "agent");
            }
            __syncthreads();

            const f16* A = isP ? (h1all + (size_t)t * NB * NH)
                               : (t > 0 ? h2all + (size_t)(t - 1) * NB * NH : nullptr);
            const bool azero = (!isP) && (t == 0);

            auto stageA = [&](int c) {
#pragma unroll
                for (int ii = 0; ii < 2; ++ii) {
                    int idx = tid + ii * 256;
                    int rt = idx >> 8, inner = idx & 255;
                    int k2 = inner >> 6, ln = inner & 63;
                    int kpos = c * 128 + k2 * 32 + (ln >> 4) * 8;
                    int rw = rt * 16 + (ln & 15);
                    f16x8 v = azero ? f16x8{}
                                    : *(const f16x8*)(A + (size_t)rw * NH + kpos);
                    *(f16x8*)(((c & 1) ? Ab1 : Ab0) + idx * 16) = v;
                }
            };

            // acc init
            f32x4 accA0 = {}, accA1 = {}, accB0 = {}, accB1 = {};
            if (!isP) {
                const float* xr = xp2ring + (size_t)(t & 15) * NB * NG;
#pragma unroll
                for (int r = 0; r < 4; ++r) {
                    unsigned u0 = __hip_atomic_load(
                        (const unsigned*)(xr + (size_t)(0 * 16 + lhi * 4 + r) * NG + w * NH + ubase + llo),
                        __ATOMIC_RELAXED, __HIP_MEMORY_SCOPE_AGENT);
                    unsigned u1 = __hip_atomic_load(
                        (const unsigned*)(xr + (size_t)(1 * 16 + lhi * 4 + r) * NG + w * NH + ubase + llo),
                        __ATOMIC_RELAXED, __HIP_MEMORY_SCOPE_AGENT);
                    accA0[r] = __uint_as_float(u0) + biasw;
                    accB0[r] = __uint_as_float(u1) + biasw;
                }
            }

            stageA(0);
            __syncthreads();
            for (int ch = 0; ch < 8; ++ch) {
                if (ch < 7) stageA(ch + 1);
                const char* ab = (ch & 1) ? Ab1 : Ab0;
#pragma unroll
                for (int k2 = 0; k2 < 4; ++k2) {
                    int ks = ch * 4 + k2;
                    f16x8 bfr = *(const f16x8*)(WL + (((size_t)(w * KST + ks) << 6) + lane) * 16);
                    f16x8 a0 = *(const f16x8*)(ab + (((0 * 4 + k2) << 6) + lane) * 16);
                    f16x8 a1 = *(const f16x8*)(ab + (((1 * 4 + k2) << 6) + lane) * 16);
                    if (k2 & 1) {
                        accA1 = __builtin_amdgcn_mfma_f32_16x16x32_f16(a0, bfr, accA1, 0, 0, 0);
                        accB1 = __builtin_amdgcn_mfma_f32_16x16x32_f16(a1, bfr, accB1, 0, 0, 0);
                    } else {
                        accA0 = __builtin_amdgcn_mfma_f32_16x16x32_f16(a0, bfr, accA0, 0, 0, 0);
                        accB0 = __builtin_amdgcn_mfma_f32_16x16x32_f16(a1, bfr, accB0, 0, 0, 0);
                    }
                }
                __syncthreads();
            }
            f32x4 gA = accA0 + accA1;
            f32x4 gB = accB0 + accB1;

            if (isP) {
                float* xo = xp2ring + (size_t)(t & 15) * NB * NG;
#pragma unroll
                for (int r = 0; r < 4; ++r) {
                    __hip_atomic_store(xo + (size_t)(0 * 16 + lhi * 4 + r) * NG + w * NH + ubase + llo,
                                       gA[r], __ATOMIC_RELAXED, __HIP_MEMORY_SCOPE_AGENT);
                    __hip_atomic_store(xo + (size_t)(1 * 16 + lhi * 4 + r) * NG + w * NH + ubase + llo,
                                       gB[r], __ATOMIC_RELAXED, __HIP_MEMORY_SCOPE_AGENT);
                }
                __syncthreads();
                if (tid == 0) {
                    __builtin_amdgcn_fence(__ATOMIC_RELEASE, "agent");
                    __hip_atomic_store(flagsp + (size_t)t * 64 + q, 1u,
                                       __ATOMIC_RELAXED, __HIP_MEMORY_SCOPE_AGENT);
                }
            } else {
#pragma unroll
                for (int r = 0; r < 4; ++r) {
                    gbuf[(w * 32 + 0 * 16 + lhi * 4 + r) * 16 + llo] = gA[r];
                    gbuf[(w * 32 + 1 * 16 + lhi * 4 + r) * 16 + llo] = gB[r];
                }
                __syncthreads();
#pragma unroll
                for (int half = 0; half < 2; ++half) {
                    int rr = r0 + half * 16;
                    float gi = gbuf[(0 * 32 + rr) * 16 + j];
                    float gf = gbuf[(1 * 32 + rr) * 16 + j];
                    float gg = gbuf[(2 * 32 + rr) * 16 + j];
                    float go = gbuf[(3 * 32 + rr) * 16 + j];
                    float i_ = sigm(gi), f_ = sigm(gf), g_ = tanh_(gg), o_ = sigm(go);
                    float& cr = half ? cB : cA;
                    cr = f_ * cr + i_ * g_;
                    float h = o_ * tanh_(cr);
                    unsigned short hb = __builtin_bit_cast(unsigned short, (f16)h);
                    __hip_atomic_store((unsigned short*)(h2all + ((size_t)t * NB + rr) * NH + ubase + j),
                                       hb, __ATOMIC_RELAXED, __HIP_MEMORY_SCOPE_AGENT);
                }
                __syncthreads();
                if (tid == 0) {
                    __builtin_amdgcn_fence(__ATOMIC_RELEASE, "agent");
                    __hip_atomic_store(flags2 + (size_t)t * 64 + q, 1u,
                                       __ATOMIC_RELAXED, __HIP_MEMORY_SCOPE_AGENT);
                }
            }
        }
    }
}

// ---------------------------------------------------------------------------
// Head: out[b][t][o] = h2[b][t][:] @ W_out^T + b_out ; one WG per t  (from R1 run)
// ---------------------------------------------------------------------------
__device__ __forceinline__ void stage_h(const f16* __restrict__ hsrc, char* smem, int tid) {
    const float4* src = (const float4*)hsrc;
#pragma unroll
    for (int i = 0; i < 16; ++i) {
        int c = i * 256 + tid;
        int off = c * 16;
        int swz = off ^ (((off >> 11) & 7) << 4);
        *(float4*)(smem + swz) = src[c];
    }
}
__device__ __forceinline__ f16x8 afrag(const char* smem, int row, int kk) {
    int off = (row << 11) + kk * 2;
    off ^= ((row & 7) << 4);
    return *(const f16x8*)(smem + off);
}

__global__ __launch_bounds__(256) void head_kernel(
    const f16* __restrict__ h2all, const f16* __restrict__ Wout,
    const float* __restrict__ bout, float* __restrict__ out)
{
    __shared__ __align__(16) char smem[65536];
    int t = blockIdx.x;
    int tid = threadIdx.x;
    int wave = tid >> 6, lane = tid & 63, lhi = lane >> 4, llo = lane & 15;
    stage_h(h2all + (size_t)t * NB * NH, smem, tid);
    __syncthreads();

    f32x4 acc[2][2];
#pragma unroll
    for (int nt = 0; nt < 2; ++nt) {
        int col = wave * 32 + nt * 16 + llo;
        float bb = bout[col];
#pragma unroll
        for (int r = 0; r < 4; ++r) { acc[0][nt][r] = bb; acc[1][nt][r] = bb; }
    }
#pragma unroll 8
    for (int kt = 0; kt < 32; ++kt) {
        int kk = kt * 32 + lhi * 8;
        f16x8 a0 = afrag(smem, llo, kk);
        f16x8 a1 = afrag(smem, 16 + llo, kk);
#pragma unroll
        for (int nt = 0; nt < 2; ++nt) {
            int col = wave * 32 + nt * 16 + llo;
            f16x8 bf = *(const f16x8*)(Wout + (size_t)col * NH + kk);
            acc[0][nt] = __builtin_amdgcn_mfma_f32_16x16x32_f16(a0, bf, acc[0][nt], 0, 0, 0);
            acc[1][nt] = __builtin_amdgcn_mfma_f32_16x16x32_f16(a1, bf, acc[1][nt], 0, 0, 0);
        }
    }
#pragma unroll
    for (int nt = 0; nt < 2; ++nt) {
        int col = wave * 32 + nt * 16 + llo;
#pragma unroll
        for (int r = 0; r < 4; ++r) {
            out[(size_t)(lhi * 4 + r) * NT * NO + (size_t)t * NO + col] = acc[0][nt][r];
            out[(size_t)(16 + lhi * 4 + r) * NT * NO + (size_t)t * NO + col] = acc[1][nt][r];
        }
    }
}

extern "C" void kernel_launch(void* const* d_in, const int* in_sizes, int n_in,
                              void* d_out, int out_size, void* d_ws, size_t ws_size,
                              hipStream_t stream)
{
    const float* state = (const float*)d_in[0];
    const float* Wih0f = (const float*)d_in[1];
    const float* Whh0f = (const float*)d_in[2];
    const float* b0    = (const float*)d_in[3];
    const float* Wih1f = (const float*)d_in[4];
    const float* Whh1f = (const float*)d_in[5];
    const float* b1    = (const float*)d_in[6];
    const float* Woutf = (const float*)d_in[7];
    const float* bout  = (const float*)d_in[8];
    float* out = (float*)d_out;
    (void)in_sizes; (void)n_in; (void)out_size; (void)ws_size;

    size_t off = 0;
    char* base = (char*)d_ws;
    auto alloc = [&](size_t bytes) -> void* {
        void* p = base + off;
        off += (bytes + 255) & ~(size_t)255;
        return p;
    };
    f16*      state16 = (f16*)alloc((size_t)NB * NT * NI * 2);
    f16*      Wout    = (f16*)alloc((size_t)NO * NH * 2);
    f16*      h1all   = (f16*)alloc((size_t)NT * NB * NH * 2);
    f16*      h2all   = (f16*)alloc((size_t)NT * NB * NH * 2);
    float*    xp2ring = (float*)alloc((size_t)16 * NB * NG * 4);
    unsigned* flags1  = (unsigned*)alloc((size_t)NT * 128 * 4);
    unsigned* flagsp  = (unsigned*)alloc((size_t)NT * 64 * 4);
    unsigned* flags2  = (unsigned*)alloc((size_t)NT * 64 * 4);

    convf16<<<(NB * NT * NI + 255) / 256, 256, 0, stream>>>(state, state16, NB * NT * NI);
    convf16<<<(NO * NH + 255) / 256, 256, 0, stream>>>(Woutf, Wout, NO * NH);
    // flags are contiguous: one memset
    hipMemsetAsync(flags1, 0, (size_t)NT * (128 + 64 + 64) * 4 + 512, stream);

    hipFuncSetAttribute((const void*)persist,
                        hipFuncAttributeMaxDynamicSharedMemorySize, 155648);
    persist<<<256, 256, 155648, stream>>>(Wih0f, Whh0f, b0, Wih1f, Whh1f, b1,
                                          state16, h1all, h2all, xp2ring,
                                          flags1, flagsp, flags2);
    head_kernel<<<NT, 256, 0, stream>>>(h2all, Wout, bout, out);
}

// Round 3
// 5891.381 us; speedup vs baseline: 1.0341x; 1.0341x over previous
//
#include <hip/hip_runtime.h>

#define NB 32
#define NT 512
#define NI 128
#define NH 1024
#define NG 4096
#define NO 128
#define RING 32

typedef _Float16 f16;
typedef _Float16 f16x8 __attribute__((ext_vector_type(8)));
typedef float f32x4 __attribute__((ext_vector_type(4)));
typedef unsigned long long ull;

__device__ __forceinline__ float sigm(float x) { return 1.f / (1.f + __expf(-x)); }
__device__ __forceinline__ float tanh_(float x) {
    float a = fabsf(x);
    float e = __expf(-2.f * a);
    float r = (1.f - e) / (1.f + e);
    return x < 0.f ? -r : r;
}
// true when NO halfword of x equals the 0x7F7F sentinel
__device__ __forceinline__ bool nosent(ull x) {
    ull y = x ^ 0x7F7F7F7F7F7F7F7FULL;
    return !(((y - 0x0001000100010001ULL) & ~y) & 0x8000800080008000ULL);
}
__device__ __forceinline__ ull aload64(const void* p) {
    return __hip_atomic_load((const ull*)p, __ATOMIC_RELAXED, __HIP_MEMORY_SCOPE_AGENT);
}
__device__ __forceinline__ float aload32f(const void* p) {
    unsigned u = __hip_atomic_load((const unsigned*)p, __ATOMIC_RELAXED, __HIP_MEMORY_SCOPE_AGENT);
    return __uint_as_float(u);
}
__device__ __forceinline__ void astore16(void* p, f16 v) {
    __hip_atomic_store((unsigned short*)p, __builtin_bit_cast(unsigned short, v),
                       __ATOMIC_RELAXED, __HIP_MEMORY_SCOPE_AGENT);
}
__device__ __forceinline__ void astore32(void* p, float v) {
    __hip_atomic_store((unsigned*)p, __float_as_uint(v),
                       __ATOMIC_RELAXED, __HIP_MEMORY_SCOPE_AGENT);
}
__device__ __forceinline__ f16x8 ld8f(const float* s) {
    float4 x0 = *(const float4*)s, x1 = *(const float4*)(s + 4);
    f16x8 v;
    v[0] = (f16)x0.x; v[1] = (f16)x0.y; v[2] = (f16)x0.z; v[3] = (f16)x0.w;
    v[4] = (f16)x1.x; v[5] = (f16)x1.y; v[6] = (f16)x1.z; v[7] = (f16)x1.w;
    return v;
}

__global__ void convf16(const float* __restrict__ src, f16* __restrict__ dst, int n) {
    int i = blockIdx.x * blockDim.x + threadIdx.x;
    if (i < n) dst[i] = (f16)src[i];
}

// ---------------------------------------------------------------------------
// Persistent pipeline: 256 WGs x 256 thr, 1 WG/CU (forced by 96KB dyn LDS).
//  bid [0,128)   R1: layer-1 step, (16 batch, 16 units)/CU, K=1152 (state|h1).
//  bid [128,192) P : xp2[t] = h1[t] @ W_ih1^T (no bias), 16 units, 32 batch.
//  bid [192,256) R2: layer-2 step, 16 units, 32 batch, K=1024 (h2).
// Weights live in VGPRs (K-split x 4 gates per wave). A staged via LDS once
// per step. Cross-CU h passed through L3 with 0x7F7F f16-NaN sentinel +
// relaxed agent atomic loads (no flags, no fences on critical path).
// xp2 ring (depth 32) is flag-gated per (t, unit-slice).
// ---------------------------------------------------------------------------
extern "C" __global__ __launch_bounds__(256, 1) void persist(
    const float* __restrict__ Wih0f, const float* __restrict__ Whh0f, const float* __restrict__ b0,
    const float* __restrict__ Wih1f, const float* __restrict__ Whh1f, const float* __restrict__ b1,
    const f16* __restrict__ state16,
    f16* __restrict__ h1all,      // [NT][NB][NH], 0x7F-filled
    f16* __restrict__ h2all,      // [NT][NB][NH], 0x7F-filled
    float* __restrict__ xp2ring,  // [RING][NB][NG]
    unsigned* __restrict__ flagsp,  // [NT][64]
    unsigned* __restrict__ flags2)  // [NT][64]
{
    extern __shared__ char smem[];
    const int bid = blockIdx.x;
    const int tid = threadIdx.x;
    const int w = tid >> 6;
    const int lane = tid & 63;
    const int llo = lane & 15;
    const int lhi = lane >> 4;
    const int eu = tid & 15;      // elementwise: unit
    const int eb = tid >> 4;      // elementwise: batch row (0..15)

    if (bid < 128) {
        // ============================ R1 ============================
        const int bs = bid >> 6, us = bid & 63;
        const int bbase = bs * 16, ubase = us * 16;
        // weights in regs: wave w holds ks = w*9+i (i<9), all 4 gates
        f16x8 wr[4][9];
#pragma unroll
        for (int g = 0; g < 4; ++g)
#pragma unroll
            for (int i = 0; i < 9; ++i) {
                int ks = w * 9 + i, kpos = ks * 32 + lhi * 8;
                int col = g * NH + ubase + llo;
                const float* s = (kpos < 128) ? (Wih0f + (size_t)col * NI + kpos)
                                              : (Whh0f + (size_t)col * NH + (kpos - 128));
                wr[g][i] = ld8f(s);
            }
        const float B0 = b0[0 * NH + ubase + eu], B1 = b0[1 * NH + ubase + eu];
        const float B2 = b0[2 * NH + ubase + eu], B3 = b0[3 * NH + ubase + eu];
        float c_ = 0.f;
        char* Ab = smem;                         // 36 KB: [ks 0..35][lane]*16B
        float* gbuf = (float*)(smem + 36864);    // 16 KB: [w][g][col][row]

        for (int t = 0; t < NT; ++t) {
            // ---- stage A (sentinel): issue ALL loads first, then validate ----
            const int grp = tid >> 6;
            f16x8 val[9];
            ull va[9], vb[9];
            unsigned pend = 0;
#pragma unroll
            for (int i = 0; i < 9; ++i) {
                int ks = grp * 9 + i, kpos = ks * 32 + lhi * 8;
                int row = bbase + llo;
                if (kpos < 128) {
                    val[i] = *(const f16x8*)(state16 + ((size_t)row * NT + t) * NI + kpos);
                } else if (t > 0) {
                    const char* p = (const char*)(h1all + ((size_t)(t - 1) * NB + row) * NH + (kpos - 128));
                    va[i] = aload64(p);
                    vb[i] = aload64(p + 8);
                }
            }
#pragma unroll
            for (int i = 0; i < 9; ++i) {
                int ks = grp * 9 + i, kpos = ks * 32 + lhi * 8;
                if (kpos < 128) continue;
                if (t == 0) { val[i] = 0; continue; }
                if (nosent(va[i]) && nosent(vb[i])) {
                    ((ull*)&val[i])[0] = va[i]; ((ull*)&val[i])[1] = vb[i];
                } else pend |= 1u << i;
            }
            while (pend) {
#pragma unroll
                for (int i = 0; i < 9; ++i)
                    if (pend & (1u << i)) {
                        int ks = grp * 9 + i, kpos = ks * 32 + lhi * 8;
                        const char* p = (const char*)(h1all + ((size_t)(t - 1) * NB + bbase + llo) * NH + (kpos - 128));
                        ull a = aload64(p), b = aload64(p + 8);
                        if (nosent(a) && nosent(b)) {
                            ((ull*)&val[i])[0] = a; ((ull*)&val[i])[1] = b;
                            pend &= ~(1u << i);
                        }
                    }
                if (pend) __builtin_amdgcn_s_sleep(1);
            }
#pragma unroll
            for (int i = 0; i < 9; ++i) {
                int ks = grp * 9 + i;
                *(f16x8*)(Ab + ((size_t)ks * 64 + lane) * 16) = val[i];
            }
            __syncthreads();

            // ---- MFMA: wave w does its 9 K-slices for all 4 gates ----
            f32x4 acc[4];
#pragma unroll
            for (int g = 0; g < 4; ++g) acc[g] = 0.f;
#pragma unroll
            for (int i = 0; i < 9; ++i) {
                f16x8 a = *(const f16x8*)(Ab + ((size_t)(w * 9 + i) * 64 + lane) * 16);
#pragma unroll
                for (int g = 0; g < 4; ++g)
                    acc[g] = __builtin_amdgcn_mfma_f32_16x16x32_f16(a, wr[g][i], acc[g], 0, 0, 0);
            }
            // partials: gbuf[w][g][col=llo][row=lhi*4+r]
#pragma unroll
            for (int g = 0; g < 4; ++g)
                *(f32x4*)(gbuf + ((w * 4 + g) * 256 + llo * 16 + lhi * 4)) = acc[g];
            __syncthreads();

            // ---- reduce + elementwise; thread owns (unit=eu, batch=eb) ----
            float gv[4];
#pragma unroll
            for (int g = 0; g < 4; ++g) {
                float s0 = gbuf[(0 * 4 + g) * 256 + eu * 16 + eb];
                float s1 = gbuf[(1 * 4 + g) * 256 + eu * 16 + eb];
                float s2 = gbuf[(2 * 4 + g) * 256 + eu * 16 + eb];
                float s3 = gbuf[(3 * 4 + g) * 256 + eu * 16 + eb];
                gv[g] = (s0 + s1) + (s2 + s3);
            }
            float i_ = sigm(gv[0] + B0), f_ = sigm(gv[1] + B1);
            float g_ = tanh_(gv[2] + B2), o_ = sigm(gv[3] + B3);
            c_ = f_ * c_ + i_ * g_;
            float h = o_ * tanh_(c_);
            astore16(h1all + ((size_t)t * NB + bbase + eb) * NH + ubase + eu, (f16)h);
        }
    } else {
        // ========================= P / R2 =========================
        const bool isP = (bid < 192);
        const int q = isP ? (bid - 128) : (bid - 192);
        const int ubase = q * 16;
        const float* Wsrc = isP ? Wih1f : Whh1f;
        f16x8 wr[4][8];
#pragma unroll
        for (int g = 0; g < 4; ++g)
#pragma unroll
            for (int i = 0; i < 8; ++i) {
                int ks = w * 8 + i, kpos = ks * 32 + lhi * 8;
                int col = g * NH + ubase + llo;
                wr[g][i] = ld8f(Wsrc + (size_t)col * NH + kpos);
            }
        float Bv0 = 0, Bv1 = 0, Bv2 = 0, Bv3 = 0;
        if (!isP) {
            Bv0 = b1[0 * NH + ubase + eu]; Bv1 = b1[1 * NH + ubase + eu];
            Bv2 = b1[2 * NH + ubase + eu]; Bv3 = b1[3 * NH + ubase + eu];
        }
        float cA = 0.f, cB = 0.f;
        char* Ab = smem;                          // 64 KB: [flat=rt*32+ks][lane]*16B
        float* gbuf = (float*)(smem + 65536);     // 32 KB: [w][g*2+rt][col][row]

        for (int t = 0; t < NT; ++t) {
            // ---- stage A (sentinel), loads first ----
            const int grp = tid >> 6;
            const f16* A = isP ? (h1all + (size_t)t * NB * NH)
                               : (h2all + (size_t)(t - 1) * NB * NH);
            const bool azero = (!isP) && (t == 0);
            f16x8 val[16];
            ull va[16], vb[16];
            unsigned pend = 0;
            if (!azero) {
#pragma unroll
                for (int i = 0; i < 16; ++i) {
                    int flat = grp * 16 + i;
                    int rt = flat >> 5, ks = flat & 31;
                    int row = rt * 16 + llo, kpos = ks * 32 + lhi * 8;
                    const char* p = (const char*)(A + (size_t)row * NH + kpos);
                    va[i] = aload64(p);
                    vb[i] = aload64(p + 8);
                }
            }
            // off-critical-path flag polls while loads are in flight
            if (tid == 0) {
                if (isP) {
                    if (t >= RING)
                        while (!__hip_atomic_load(flags2 + (size_t)(t - RING) * 64 + q,
                                                  __ATOMIC_RELAXED, __HIP_MEMORY_SCOPE_AGENT))
                            __builtin_amdgcn_s_sleep(8);
                } else {
                    while (!__hip_atomic_load(flagsp + (size_t)t * 64 + q,
                                              __ATOMIC_RELAXED, __HIP_MEMORY_SCOPE_AGENT))
                        __builtin_amdgcn_s_sleep(2);
                }
            }
            if (azero) {
#pragma unroll
                for (int i = 0; i < 16; ++i) val[i] = 0;
            } else {
#pragma unroll
                for (int i = 0; i < 16; ++i) {
                    if (nosent(va[i]) && nosent(vb[i])) {
                        ((ull*)&val[i])[0] = va[i]; ((ull*)&val[i])[1] = vb[i];
                    } else pend |= 1u << i;
                }
                while (pend) {
#pragma unroll
                    for (int i = 0; i < 16; ++i)
                        if (pend & (1u << i)) {
                            int flat = grp * 16 + i;
                            int rt = flat >> 5, ks = flat & 31;
                            const char* p = (const char*)(A + (size_t)(rt * 16 + llo) * NH + ks * 32 + lhi * 8);
                            ull a = aload64(p), b = aload64(p + 8);
                            if (nosent(a) && nosent(b)) {
                                ((ull*)&val[i])[0] = a; ((ull*)&val[i])[1] = b;
                                pend &= ~(1u << i);
                            }
                        }
                    if (pend) __builtin_amdgcn_s_sleep(1);
                }
            }
#pragma unroll
            for (int i = 0; i < 16; ++i)
                *(f16x8*)(Ab + ((size_t)(grp * 16 + i) * 64 + lane) * 16) = val[i];
            __syncthreads();

            // ---- MFMA: wave w: ks = w*8+i, 2 row-tiles x 4 gates ----
            f32x4 acc[2][4];
#pragma unroll
            for (int rt = 0; rt < 2; ++rt)
#pragma unroll
                for (int g = 0; g < 4; ++g) acc[rt][g] = 0.f;
#pragma unroll
            for (int i = 0; i < 8; ++i) {
                int ks = w * 8 + i;
                f16x8 a0 = *(const f16x8*)(Ab + ((size_t)(0 * 32 + ks) * 64 + lane) * 16);
                f16x8 a1 = *(const f16x8*)(Ab + ((size_t)(1 * 32 + ks) * 64 + lane) * 16);
#pragma unroll
                for (int g = 0; g < 4; ++g) {
                    acc[0][g] = __builtin_amdgcn_mfma_f32_16x16x32_f16(a0, wr[g][i], acc[0][g], 0, 0, 0);
                    acc[1][g] = __builtin_amdgcn_mfma_f32_16x16x32_f16(a1, wr[g][i], acc[1][g], 0, 0, 0);
                }
            }
#pragma unroll
            for (int rt = 0; rt < 2; ++rt)
#pragma unroll
                for (int g = 0; g < 4; ++g)
                    *(f32x4*)(gbuf + ((w * 8 + g * 2 + rt) * 256 + llo * 16 + lhi * 4)) = acc[rt][g];
            __syncthreads();

            if (isP) {
                // reduce + store to ring; thread owns (eu, eb) x 2 row-tiles
                float* xo = xp2ring + (size_t)(t & (RING - 1)) * NB * NG;
#pragma unroll
                for (int g = 0; g < 4; ++g)
#pragma unroll
                    for (int rt = 0; rt < 2; ++rt) {
                        float s = 0.f;
#pragma unroll
                        for (int w2 = 0; w2 < 4; ++w2)
                            s += gbuf[(w2 * 8 + g * 2 + rt) * 256 + eu * 16 + eb];
                        astore32(xo + (size_t)(rt * 16 + eb) * NG + g * NH + ubase + eu, s);
                    }
                __syncthreads();
                if (tid == 0)
                    __hip_atomic_store(flagsp + (size_t)t * 64 + q, 1u,
                                       __ATOMIC_RELAXED, __HIP_MEMORY_SCOPE_AGENT);
            } else {
                const float* xr = xp2ring + (size_t)(t & (RING - 1)) * NB * NG;
#pragma unroll
                for (int rt = 0; rt < 2; ++rt) {
                    float gv[4];
#pragma unroll
                    for (int g = 0; g < 4; ++g) {
                        float s = aload32f(xr + (size_t)(rt * 16 + eb) * NG + g * NH + ubase + eu);
#pragma unroll
                        for (int w2 = 0; w2 < 4; ++w2)
                            s += gbuf[(w2 * 8 + g * 2 + rt) * 256 + eu * 16 + eb];
                        gv[g] = s;
                    }
                    float i_ = sigm(gv[0] + Bv0), f_ = sigm(gv[1] + Bv1);
                    float g_ = tanh_(gv[2] + Bv2), o_ = sigm(gv[3] + Bv3);
                    float& cr = rt ? cB : cA;
                    cr = f_ * cr + i_ * g_;
                    float h = o_ * tanh_(cr);
                    astore16(h2all + ((size_t)t * NB + rt * 16 + eb) * NH + ubase + eu, (f16)h);
                }
                __syncthreads();
                if (tid == 0)
                    __hip_atomic_store(flags2 + (size_t)t * 64 + q, 1u,
                                       __ATOMIC_RELAXED, __HIP_MEMORY_SCOPE_AGENT);
            }
        }
    }
}

// ---------------------------------------------------------------------------
// Head: out[b][t][o] = h2[b][t][:] @ W_out^T + b_out ; one WG per t
// ---------------------------------------------------------------------------
__device__ __forceinline__ void stage_h(const f16* __restrict__ hsrc, char* smem, int tid) {
    const float4* src = (const float4*)hsrc;
#pragma unroll
    for (int i = 0; i < 16; ++i) {
        int c = i * 256 + tid;
        int off = c * 16;
        int swz = off ^ (((off >> 11) & 7) << 4);
        *(float4*)(smem + swz) = src[c];
    }
}
__device__ __forceinline__ f16x8 afrag(const char* smem, int row, int kk) {
    int off = (row << 11) + kk * 2;
    off ^= ((row & 7) << 4);
    return *(const f16x8*)(smem + off);
}

__global__ __launch_bounds__(256) void head_kernel(
    const f16* __restrict__ h2all, const f16* __restrict__ Wout,
    const float* __restrict__ bout, float* __restrict__ out)
{
    __shared__ __align__(16) char smem[65536];
    int t = blockIdx.x;
    int tid = threadIdx.x;
    int wave = tid >> 6, lane = tid & 63, lhi = lane >> 4, llo = lane & 15;
    stage_h(h2all + (size_t)t * NB * NH, smem, tid);
    __syncthreads();

    f32x4 acc[2][2];
#pragma unroll
    for (int nt = 0; nt < 2; ++nt) {
        int col = wave * 32 + nt * 16 + llo;
        float bb = bout[col];
#pragma unroll
        for (int r = 0; r < 4; ++r) { acc[0][nt][r] = bb; acc[1][nt][r] = bb; }
    }
#pragma unroll 8
    for (int kt = 0; kt < 32; ++kt) {
        int kk = kt * 32 + lhi * 8;
        f16x8 a0 = afrag(smem, llo, kk);
        f16x8 a1 = afrag(smem, 16 + llo, kk);
#pragma unroll
        for (int nt = 0; nt < 2; ++nt) {
            int col = wave * 32 + nt * 16 + llo;
            f16x8 bf = *(const f16x8*)(Wout + (size_t)col * NH + kk);
            acc[0][nt] = __builtin_amdgcn_mfma_f32_16x16x32_f16(a0, bf, acc[0][nt], 0, 0, 0);
            acc[1][nt] = __builtin_amdgcn_mfma_f32_16x16x32_f16(a1, bf, acc[1][nt], 0, 0, 0);
        }
    }
#pragma unroll
    for (int nt = 0; nt < 2; ++nt) {
        int col = wave * 32 + nt * 16 + llo;
#pragma unroll
        for (int r = 0; r < 4; ++r) {
            out[(size_t)(lhi * 4 + r) * NT * NO + (size_t)t * NO + col] = acc[0][nt][r];
            out[(size_t)(16 + lhi * 4 + r) * NT * NO + (size_t)t * NO + col] = acc[1][nt][r];
        }
    }
}

extern "C" void kernel_launch(void* const* d_in, const int* in_sizes, int n_in,
                              void* d_out, int out_size, void* d_ws, size_t ws_size,
                              hipStream_t stream)
{
    const float* state = (const float*)d_in[0];
    const float* Wih0f = (const float*)d_in[1];
    const float* Whh0f = (const float*)d_in[2];
    const float* b0    = (const float*)d_in[3];
    const float* Wih1f = (const float*)d_in[4];
    const float* Whh1f = (const float*)d_in[5];
    const float* b1    = (const float*)d_in[6];
    const float* Woutf = (const float*)d_in[7];
    const float* bout  = (const float*)d_in[8];
    float* out = (float*)d_out;
    (void)in_sizes; (void)n_in; (void)out_size; (void)ws_size;

    size_t off = 0;
    char* base = (char*)d_ws;
    auto alloc = [&](size_t bytes) -> void* {
        void* p = base + off;
        off += (bytes + 255) & ~(size_t)255;
        return p;
    };
    f16*      state16 = (f16*)alloc((size_t)NB * NT * NI * 2);
    f16*      Wout    = (f16*)alloc((size_t)NO * NH * 2);
    f16*      h1all   = (f16*)alloc((size_t)NT * NB * NH * 2);
    f16*      h2all   = (f16*)alloc((size_t)NT * NB * NH * 2);
    float*    xp2ring = (float*)alloc((size_t)RING * NB * NG * 4);
    unsigned* flagsp  = (unsigned*)alloc((size_t)NT * 64 * 4);
    unsigned* flags2  = (unsigned*)alloc((size_t)NT * 64 * 4);

    convf16<<<(NB * NT * NI + 255) / 256, 256, 0, stream>>>(state, state16, NB * NT * NI);
    convf16<<<(NO * NH + 255) / 256, 256, 0, stream>>>(Woutf, Wout, NO * NH);
    // sentinel-fill h1all+h2all (contiguous), zero flags (contiguous)
    hipMemsetAsync(h1all, 0x7F, (size_t)2 * NT * NB * NH * 2, stream);
    hipMemsetAsync(flagsp, 0, (size_t)2 * NT * 64 * 4, stream);

    hipFuncSetAttribute((const void*)persist,
                        hipFuncAttributeMaxDynamicSharedMemorySize, 98304);
    persist<<<256, 256, 98304, stream>>>(Wih0f, Whh0f, b0, Wih1f, Whh1f, b1,
                                         state16, h1all, h2all, xp2ring,
                                         flagsp, flags2);
    head_kernel<<<NT, 256, 0, stream>>>(h2all, Wout, bout, out);
}

// Round 4
// 3829.036 us; speedup vs baseline: 1.5911x; 1.5386x over previous
//
#include <hip/hip_runtime.h>

#define NB 32
#define NT 512
#define NI 128
#define NH 1024
#define NG 4096
#define NO 128

typedef _Float16 f16;
typedef _Float16 f16x8 __attribute__((ext_vector_type(8)));
typedef float f32x4 __attribute__((ext_vector_type(4)));
typedef unsigned long long ull;

#define MFMA16(a, b, c) __builtin_amdgcn_mfma_f32_16x16x32_f16(a, b, c, 0, 0, 0)

__device__ __forceinline__ float sigm(float x) { return 1.f / (1.f + __expf(-x)); }
__device__ __forceinline__ float tanh_(float x) {
    float a = fabsf(x);
    float e = __expf(-2.f * a);
    float r = (1.f - e) / (1.f + e);
    return x < 0.f ? -r : r;
}
// true when NO halfword of x equals the 0x7F7F sentinel (f16 NaN pattern;
// |h|<1 and gate pre-activations never encode as it)
__device__ __forceinline__ bool nosent(ull x) {
    ull y = x ^ 0x7F7F7F7F7F7F7F7FULL;
    return !(((y - 0x0001000100010001ULL) & ~y) & 0x8000800080008000ULL);
}
__device__ __forceinline__ ull aload64(const void* p) {
    return __hip_atomic_load((const ull*)p, __ATOMIC_RELAXED, __HIP_MEMORY_SCOPE_AGENT);
}
__device__ __forceinline__ void astore64(void* p, ull v) {
    __hip_atomic_store((ull*)p, v, __ATOMIC_RELAXED, __HIP_MEMORY_SCOPE_AGENT);
}
__device__ __forceinline__ f16x8 ld8f(const float* s) {
    float4 x0 = *(const float4*)s, x1 = *(const float4*)(s + 4);
    f16x8 v;
    v[0] = (f16)x0.x; v[1] = (f16)x0.y; v[2] = (f16)x0.z; v[3] = (f16)x0.w;
    v[4] = (f16)x1.x; v[5] = (f16)x1.y; v[6] = (f16)x1.z; v[7] = (f16)x1.w;
    return v;
}

__global__ void convf16(const float* __restrict__ src, f16* __restrict__ dst, int n) {
    int i = blockIdx.x * blockDim.x + threadIdx.x;
    if (i < n) dst[i] = (f16)src[i];
}

// ---------------------------------------------------------------------------
// Persistent pipeline: 256 WGs x 256 thr, 1 WG/CU (forced by 84KB dyn LDS +
// high VGPR count).
//  bid [0,128)   R1: layer-1 step, (16 batch, 16 units)/CU, K=1152 (state|h1).
//  bid [128,256) R2: layer-2 step + input proj, (16 batch, 16 units)/CU,
//                two K=1024 matmuls (h1[t]@Wih1 + h2[t-1]@Whh1).
// All weights in VGPRs (K split across 4 waves, 4 gates). A-fragments go
// straight from global loads into MFMA (no LDS staging). Cross-CU h passes
// through L3: producers publish packed 8B agent-scope atomic stores
// (L2-bypass); consumers bulk-read with PLAIN dwordx4 loads (streaming) and
// fall back to atomic loads only for fragments still holding the 0x7F7F
// sentinel. No flags, no fences, no rings -> deadlock-impossible dataflow.
// LDS holds only the 17-padded cross-wave K-reduction buffer.
// ---------------------------------------------------------------------------
extern "C" __global__ __launch_bounds__(256, 1) void persist(
    const float* __restrict__ Wih0f, const float* __restrict__ Whh0f, const float* __restrict__ b0,
    const float* __restrict__ Wih1f, const float* __restrict__ Whh1f, const float* __restrict__ b1,
    const f16* __restrict__ state16,
    f16* __restrict__ h1all,      // [NT][NB][NH], 0x7F-filled
    f16* __restrict__ h2all)      // [NT][NB][NH], 0x7F-filled
{
    extern __shared__ char smem[];
    float* gbuf = (float*)smem;   // [16][16*17] f32 partials, +17 pad
    const int bid = blockIdx.x;
    const int tid = threadIdx.x;
    const int w = tid >> 6;
    const int lane = tid & 63;
    const int llo = lane & 15;
    const int lhi = lane >> 4;
    const int rb = tid >> 2;        // elementwise: batch row (threads 0..63)
    const int uq = (tid & 3) * 4;   // elementwise: unit quad base

    if (bid < 128) {
        // ============================ R1 ============================
        const int bs = bid >> 6, us = bid & 63;
        const int bbase = bs * 16, ubase = us * 16;
        // weights: wave w owns ks = w*9+i (K=1152), 4 gate-columns blocks
        f16x8 wr[36];
#pragma unroll
        for (int g = 0; g < 4; ++g)
#pragma unroll
            for (int i = 0; i < 9; ++i) {
                int kpos = (w * 9 + i) * 32 + lhi * 8;
                int col = g * NH + ubase + llo;
                const float* s = (kpos < 128) ? (Wih0f + (size_t)col * NI + kpos)
                                              : (Whh0f + (size_t)col * NH + (kpos - 128));
                wr[g * 9 + i] = ld8f(s);
            }
        float cc[4] = {0.f, 0.f, 0.f, 0.f};
        float Bi[4], Bff[4], Bg[4], Bo[4];
        if (tid < 64) {
#pragma unroll
            for (int u = 0; u < 4; ++u) {
                Bi[u]  = b0[0 * NH + ubase + uq + u];
                Bff[u] = b0[1 * NH + ubase + uq + u];
                Bg[u]  = b0[2 * NH + ubase + uq + u];
                Bo[u]  = b0[3 * NH + ubase + uq + u];
            }
        }

        for (int t = 0; t < NT; ++t) {
            const f16* hprev = h1all + (size_t)(t - 1) * NB * NH;
            const int row = bbase + llo;
            // ---- bulk plain loads (streaming), sentinel-validate, atomic retry ----
            f16x8 val[9];
            unsigned pend = 0;
#pragma unroll
            for (int i = 0; i < 9; ++i) {
                int kpos = (w * 9 + i) * 32 + lhi * 8;
                if (kpos < 128)
                    val[i] = *(const f16x8*)(state16 + ((size_t)row * NT + t) * NI + kpos);
                else if (t > 0)
                    val[i] = *(const f16x8*)(hprev + (size_t)row * NH + (kpos - 128));
                else
                    val[i] = f16x8{};
            }
            if (t > 0) {
#pragma unroll
                for (int i = 0; i < 9; ++i) {
                    int kpos = (w * 9 + i) * 32 + lhi * 8;
                    if (kpos >= 128) {
                        ull a = ((ull*)&val[i])[0], b = ((ull*)&val[i])[1];
                        if (!(nosent(a) && nosent(b))) pend |= 1u << i;
                    }
                }
                while (__builtin_expect(pend != 0, 0)) {
#pragma unroll
                    for (int i = 0; i < 9; ++i)
                        if (pend & (1u << i)) {
                            int kpos = (w * 9 + i) * 32 + lhi * 8;
                            const char* p = (const char*)(hprev + (size_t)row * NH + (kpos - 128));
                            ull a = aload64(p), b = aload64(p + 8);
                            if (nosent(a) && nosent(b)) {
                                ((ull*)&val[i])[0] = a; ((ull*)&val[i])[1] = b;
                                pend &= ~(1u << i);
                            }
                        }
                    if (pend) __builtin_amdgcn_s_sleep(1);
                }
            }
            // ---- MFMA directly on loaded fragments (K-split partials) ----
            f32x4 acc[4] = {};
#pragma unroll
            for (int i = 0; i < 9; ++i)
#pragma unroll
                for (int g = 0; g < 4; ++g)
                    acc[g] = MFMA16(val[i], wr[g * 9 + i], acc[g]);
            __syncthreads();   // gbuf free (prev step's reads done)
#pragma unroll
            for (int g = 0; g < 4; ++g)
#pragma unroll
                for (int r = 0; r < 4; ++r)
                    gbuf[(w * 4 + g) * 272 + (lhi * 4 + r) * 17 + llo] = acc[g][r];
            __syncthreads();
            // ---- reduce + elementwise + packed publish (threads 0..63) ----
            if (tid < 64) {
                ull pack = 0;
#pragma unroll
                for (int u = 0; u < 4; ++u) {
                    int un = uq + u;
                    float s0 = 0, s1 = 0, s2 = 0, s3 = 0;
#pragma unroll
                    for (int w2 = 0; w2 < 4; ++w2) {
                        s0 += gbuf[(w2 * 4 + 0) * 272 + rb * 17 + un];
                        s1 += gbuf[(w2 * 4 + 1) * 272 + rb * 17 + un];
                        s2 += gbuf[(w2 * 4 + 2) * 272 + rb * 17 + un];
                        s3 += gbuf[(w2 * 4 + 3) * 272 + rb * 17 + un];
                    }
                    float i_ = sigm(s0 + Bi[u]), f_ = sigm(s1 + Bff[u]);
                    float g_ = tanh_(s2 + Bg[u]), o_ = sigm(s3 + Bo[u]);
                    cc[u] = f_ * cc[u] + i_ * g_;
                    float h = o_ * tanh_(cc[u]);
                    unsigned short hb = __builtin_bit_cast(unsigned short, (f16)h);
                    pack |= (ull)hb << (16 * u);
                }
                astore64(h1all + ((size_t)t * NB + bbase + rb) * NH + ubase + uq, pack);
            }
        }
    } else {
        // ====================== R2 (merged P) ======================
        const int b2 = bid - 128, bs = b2 >> 6, us = b2 & 63;
        const int bbase = bs * 16, ubase = us * 16;
        f16x8 wr1[32], wr2[32];   // Wih1, Whh1: wave w owns ks = w*8+i
#pragma unroll
        for (int g = 0; g < 4; ++g)
#pragma unroll
            for (int i = 0; i < 8; ++i) {
                int kpos = (w * 8 + i) * 32 + lhi * 8;
                int col = g * NH + ubase + llo;
                wr1[g * 8 + i] = ld8f(Wih1f + (size_t)col * NH + kpos);
                wr2[g * 8 + i] = ld8f(Whh1f + (size_t)col * NH + kpos);
            }
        float cc[4] = {0.f, 0.f, 0.f, 0.f};
        float Bi[4], Bff[4], Bg[4], Bo[4];
        if (tid < 64) {
#pragma unroll
            for (int u = 0; u < 4; ++u) {
                Bi[u]  = b1[0 * NH + ubase + uq + u];
                Bff[u] = b1[1 * NH + ubase + uq + u];
                Bg[u]  = b1[2 * NH + ubase + uq + u];
                Bo[u]  = b1[3 * NH + ubase + uq + u];
            }
        }
        const int row = bbase + llo;

        auto check8 = [&](f16x8* v) -> unsigned {
            unsigned p = 0;
#pragma unroll
            for (int i = 0; i < 8; ++i) {
                ull a = ((ull*)&v[i])[0], b = ((ull*)&v[i])[1];
                if (!(nosent(a) && nosent(b))) p |= 1u << i;
            }
            return p;
        };
        auto retry8 = [&](const f16* A, f16x8* v, unsigned p) {
            while (__builtin_expect(p != 0, 0)) {
#pragma unroll
                for (int i = 0; i < 8; ++i)
                    if (p & (1u << i)) {
                        int kpos = (w * 8 + i) * 32 + lhi * 8;
                        const char* q = (const char*)(A + (size_t)row * NH + kpos);
                        ull a = aload64(q), b = aload64(q + 8);
                        if (nosent(a) && nosent(b)) {
                            ((ull*)&v[i])[0] = a; ((ull*)&v[i])[1] = b;
                            p &= ~(1u << i);
                        }
                    }
                if (p) __builtin_amdgcn_s_sleep(1);
            }
        };

        for (int t = 0; t < NT; ++t) {
            const f16* A1 = h1all + (size_t)t * NB * NH;
            const f16* A2 = h2all + (size_t)(t - 1) * NB * NH;
            f16x8 v1[8], v2[8];
#pragma unroll
            for (int i = 0; i < 8; ++i) {
                int kpos = (w * 8 + i) * 32 + lhi * 8;
                v1[i] = *(const f16x8*)(A1 + (size_t)row * NH + kpos);
            }
            if (t > 0) {
#pragma unroll
                for (int i = 0; i < 8; ++i) {
                    int kpos = (w * 8 + i) * 32 + lhi * 8;
                    v2[i] = *(const f16x8*)(A2 + (size_t)row * NH + kpos);
                }
                retry8(A2, v2, check8(v2));
            } else {
#pragma unroll
                for (int i = 0; i < 8; ++i) v2[i] = f16x8{};
            }
            retry8(A1, v1, check8(v1));

            f32x4 acc[4] = {};
#pragma unroll
            for (int i = 0; i < 8; ++i)
#pragma unroll
                for (int g = 0; g < 4; ++g) {
                    acc[g] = MFMA16(v1[i], wr1[g * 8 + i], acc[g]);
                    acc[g] = MFMA16(v2[i], wr2[g * 8 + i], acc[g]);
                }
            __syncthreads();
#pragma unroll
            for (int g = 0; g < 4; ++g)
#pragma unroll
                for (int r = 0; r < 4; ++r)
                    gbuf[(w * 4 + g) * 272 + (lhi * 4 + r) * 17 + llo] = acc[g][r];
            __syncthreads();
            if (tid < 64) {
                ull pack = 0;
#pragma unroll
                for (int u = 0; u < 4; ++u) {
                    int un = uq + u;
                    float s0 = 0, s1 = 0, s2 = 0, s3 = 0;
#pragma unroll
                    for (int w2 = 0; w2 < 4; ++w2) {
                        s0 += gbuf[(w2 * 4 + 0) * 272 + rb * 17 + un];
                        s1 += gbuf[(w2 * 4 + 1) * 272 + rb * 17 + un];
                        s2 += gbuf[(w2 * 4 + 2) * 272 + rb * 17 + un];
                        s3 += gbuf[(w2 * 4 + 3) * 272 + rb * 17 + un];
                    }
                    float i_ = sigm(s0 + Bi[u]), f_ = sigm(s1 + Bff[u]);
                    float g_ = tanh_(s2 + Bg[u]), o_ = sigm(s3 + Bo[u]);
                    cc[u] = f_ * cc[u] + i_ * g_;
                    float h = o_ * tanh_(cc[u]);
                    unsigned short hb = __builtin_bit_cast(unsigned short, (f16)h);
                    pack |= (ull)hb << (16 * u);
                }
                astore64(h2all + ((size_t)t * NB + bbase + rb) * NH + ubase + uq, pack);
            }
        }
    }
}

// ---------------------------------------------------------------------------
// Head: out[b][t][o] = h2[b][t][:] @ W_out^T + b_out ; one WG per t
// ---------------------------------------------------------------------------
__device__ __forceinline__ void stage_h(const f16* __restrict__ hsrc, char* smem, int tid) {
    const float4* src = (const float4*)hsrc;
#pragma unroll
    for (int i = 0; i < 16; ++i) {
        int c = i * 256 + tid;
        int off = c * 16;
        int swz = off ^ (((off >> 11) & 7) << 4);
        *(float4*)(smem + swz) = src[c];
    }
}
__device__ __forceinline__ f16x8 afrag(const char* smem, int row, int kk) {
    int off = (row << 11) + kk * 2;
    off ^= ((row & 7) << 4);
    return *(const f16x8*)(smem + off);
}

__global__ __launch_bounds__(256) void head_kernel(
    const f16* __restrict__ h2all, const f16* __restrict__ Wout,
    const float* __restrict__ bout, float* __restrict__ out)
{
    __shared__ __align__(16) char smem[65536];
    int t = blockIdx.x;
    int tid = threadIdx.x;
    int wave = tid >> 6, lane = tid & 63, lhi = lane >> 4, llo = lane & 15;
    stage_h(h2all + (size_t)t * NB * NH, smem, tid);
    __syncthreads();

    f32x4 acc[2][2];
#pragma unroll
    for (int nt = 0; nt < 2; ++nt) {
        int col = wave * 32 + nt * 16 + llo;
        float bb = bout[col];
#pragma unroll
        for (int r = 0; r < 4; ++r) { acc[0][nt][r] = bb; acc[1][nt][r] = bb; }
    }
#pragma unroll 8
    for (int kt = 0; kt < 32; ++kt) {
        int kk = kt * 32 + lhi * 8;
        f16x8 a0 = afrag(smem, llo, kk);
        f16x8 a1 = afrag(smem, 16 + llo, kk);
#pragma unroll
        for (int nt = 0; nt < 2; ++nt) {
            int col = wave * 32 + nt * 16 + llo;
            f16x8 bf = *(const f16x8*)(Wout + (size_t)col * NH + kk);
            acc[0][nt] = MFMA16(a0, bf, acc[0][nt]);
            acc[1][nt] = MFMA16(a1, bf, acc[1][nt]);
        }
    }
#pragma unroll
    for (int nt = 0; nt < 2; ++nt) {
        int col = wave * 32 + nt * 16 + llo;
#pragma unroll
        for (int r = 0; r < 4; ++r) {
            out[(size_t)(lhi * 4 + r) * NT * NO + (size_t)t * NO + col] = acc[0][nt][r];
            out[(size_t)(16 + lhi * 4 + r) * NT * NO + (size_t)t * NO + col] = acc[1][nt][r];
        }
    }
}

extern "C" void kernel_launch(void* const* d_in, const int* in_sizes, int n_in,
                              void* d_out, int out_size, void* d_ws, size_t ws_size,
                              hipStream_t stream)
{
    const float* state = (const float*)d_in[0];
    const float* Wih0f = (const float*)d_in[1];
    const float* Whh0f = (const float*)d_in[2];
    const float* b0    = (const float*)d_in[3];
    const float* Wih1f = (const float*)d_in[4];
    const float* Whh1f = (const float*)d_in[5];
    const float* b1    = (const float*)d_in[6];
    const float* Woutf = (const float*)d_in[7];
    const float* bout  = (const float*)d_in[8];
    float* out = (float*)d_out;
    (void)in_sizes; (void)n_in; (void)out_size; (void)ws_size;

    size_t off = 0;
    char* base = (char*)d_ws;
    auto alloc = [&](size_t bytes) -> void* {
        void* p = base + off;
        off += (bytes + 255) & ~(size_t)255;
        return p;
    };
    f16* state16 = (f16*)alloc((size_t)NB * NT * NI * 2);
    f16* Wout    = (f16*)alloc((size_t)NO * NH * 2);
    f16* h1all   = (f16*)alloc((size_t)NT * NB * NH * 2);
    f16* h2all   = (f16*)alloc((size_t)NT * NB * NH * 2);

    convf16<<<(NB * NT * NI + 255) / 256, 256, 0, stream>>>(state, state16, NB * NT * NI);
    convf16<<<(NO * NH + 255) / 256, 256, 0, stream>>>(Woutf, Wout, NO * NH);
    // sentinel-fill h1all+h2all (contiguous) — also erases harness poison
    hipMemsetAsync(h1all, 0x7F, (size_t)2 * NT * NB * NH * 2, stream);

    hipFuncSetAttribute((const void*)persist,
                        hipFuncAttributeMaxDynamicSharedMemorySize, 86016);
    persist<<<256, 256, 86016, stream>>>(Wih0f, Whh0f, b0, Wih1f, Whh1f, b1,
                                         state16, h1all, h2all);
    head_kernel<<<NT, 256, 0, stream>>>(h2all, Wout, bout, out);
}